// Round 7
// baseline (400.166 us; speedup 1.0000x reference)
//
#include <hip/hip_runtime.h>
#include <cmath>

// Temporal Contrast Enhancement — R9: LDS-free sweeps, barrier-free waves.
// R6 post-mortem: 2 waves/SIMD didn't move VALUBusy (31%) — all waves sit in
// one barrier-paced block (LD -> compute -> vmcnt(0) -> ds_write -> sync), so
// they stall together; phases serialize (VALU 35us + LDS 25us + mem never
// overlap -> 113us). Root cause: the LDS staging exists only to transpose
// coalesced loads into per-thread-contiguous chunks — but at S=24 a chunk is
// 96B = 6 contiguous float4: direct global reads per thread cover a
// contiguous 6KB span per wave (every line fetched once, L2 merges). So:
// drop x-staging entirely. No intra-sweep barriers, waves free-run; 1024
// threads (4 waves/SIMD) hide latency; Ac/Bc + scan in 41.7KB STATIC LDS;
// Yd/Ya/Ye in global ws. Bank conflicts and staging VALU disappear.

typedef float f32x4 __attribute__((ext_vector_type(4)));

static constexpr int   kT  = 88200;
static constexpr float kSR = 44100.0f;

// ---- fused-kernel geometry (1024 threads, S=24) ---------------------------
static constexpr int FS_    = 24;                    // chunk length (6 float4)
static constexpr int FNC_   = kT / FS_;              // 3675 chunks/series
static constexpr int FTH    = 1024;                  // threads per block
static constexpr int FNT    = (FNC_ + FTH - 1) / FTH;    // 4 tiles
static constexpr int FF4C   = FS_ / 4;               // 6 float4 per chunk

struct EnvP { float ad, bd, aa, ba, nuamp, reg; };

__device__ __forceinline__ EnvP make_params(const float* tauA, const float* tauD,
                                            const float* nu, const float* dbreg) {
  EnvP p;
  float td = fminf(fmaxf(tauD[0], 1.0f), 100.0f);
  td = fminf(fmaxf(td, 0.1f), 1000.0f) * 0.001f;
  float ta = fminf(fmaxf(tauA[0], 1.0f), 100.0f);
  ta = fminf(fmaxf(ta, 0.1f), 1000.0f) * 0.001f;
  p.ad = expf(-1.0f / (td * kSR));
  p.aa = expf(-1.0f / (ta * kSR));
  p.bd = 1.0f - p.ad;
  p.ba = 1.0f - p.aa;
  p.nuamp = exp10f(fminf(fmaxf(nu[0],    -60.0f),   0.0f) * 0.05f);
  p.reg   = exp10f(fminf(fmaxf(dbreg[0], -120.0f), -60.0f) * 0.05f);
  return p;
}

// MODE: 0=comp_d  1=comp_a(replay yd)  2=comp_e(replay yd,ya)  3=final
// Each thread loads its own contiguous 96B chunk straight from global.
// NO barriers inside — threads touch disjoint Ac/Bc entries and their own
// x/out spans; waves drift freely, spreading memory traffic in time.
template <int MODE>
__device__ __forceinline__ void sweep(const float* __restrict__ xs,
                                      float* __restrict__ os,
                                      const EnvP& p,
                                      float* __restrict__ Ac, float* __restrict__ Bc,
                                      const float* __restrict__ Ydl,
                                      const float* __restrict__ Yal,
                                      const float* __restrict__ Yel,
                                      int t) {
  const f32x4* xg4 = reinterpret_cast<const f32x4*>(xs);
#pragma unroll
  for (int it = 0; it < FNT; ++it) {
    const int c = it * FTH + t;
    if (c < FNC_) {
      const f32x4* xc = xg4 + (size_t)c * FF4C;   // c*96 bytes, 16B aligned
      // Six named staging registers — never an array, never spillable.
      f32x4 v0 = xc[0], v1 = xc[1], v2 = xc[2],
            v3 = xc[3], v4 = xc[4], v5 = xc[5];
      if (MODE == 0) {
        float A = -INFINITY, B = 0.0f;
#define STEP0(V)                                                             \
  _Pragma("unroll")                                                          \
  for (int j = 0; j < 4; ++j) {                                              \
    float xa = fabsf((V)[j]);                                                \
    float bx = p.bd * xa;                                                    \
    A = fmaxf(xa, fmaf(p.ad, A, bx));                                        \
    B = fmaf(p.ad, B, bx);                                                   \
  }
        STEP0(v0) STEP0(v1) STEP0(v2) STEP0(v3) STEP0(v4) STEP0(v5)
#undef STEP0
        Ac[c] = A; Bc[c] = B;
      } else if (MODE == 1) {
        float yd = Ydl[c];
        float A = INFINITY, B = 0.0f;
#define STEP1(V)                                                             \
  _Pragma("unroll")                                                          \
  for (int j = 0; j < 4; ++j) {                                              \
    float xa = fabsf((V)[j]);                                                \
    yd = fmaxf(xa, fmaf(p.ad, yd, p.bd * xa));                               \
    float by = p.ba * yd;                                                    \
    A = fminf(yd, fmaf(p.aa, A, by));                                        \
    B = fmaf(p.aa, B, by);                                                   \
  }
        STEP1(v0) STEP1(v1) STEP1(v2) STEP1(v3) STEP1(v4) STEP1(v5)
#undef STEP1
        Ac[c] = A; Bc[c] = B;
      } else if (MODE == 2) {
        float yd = Ydl[c], ya = Yal[c];
        float A = -INFINITY, B = 0.0f;
#define STEP2(V)                                                             \
  _Pragma("unroll")                                                          \
  for (int j = 0; j < 4; ++j) {                                              \
    float xa = fabsf((V)[j]);                                                \
    yd = fmaxf(xa, fmaf(p.ad, yd, p.bd * xa));                               \
    ya = fminf(yd, fmaf(p.aa, ya, p.ba * yd));                               \
    float et = fmaxf((yd - ya) - p.nuamp, 0.0f);                             \
    float bx = p.bd * et;                                                    \
    A = fmaxf(et, fmaf(p.ad, A, bx));                                        \
    B = fmaf(p.ad, B, bx);                                                   \
  }
        STEP2(v0) STEP2(v1) STEP2(v2) STEP2(v3) STEP2(v4) STEP2(v5)
#undef STEP2
        Ac[c] = A; Bc[c] = B;
      } else {
        float yd = Ydl[c], ya = Yal[c], ye = Yel[c];
        f32x4* oc = reinterpret_cast<f32x4*>(os) + (size_t)c * FF4C;
#define STEP3(V, OIDX)                                                       \
  {                                                                          \
    f32x4 oo;                                                                \
    _Pragma("unroll")                                                        \
    for (int j = 0; j < 4; ++j) {                                            \
      float xa = fabsf((V)[j]);                                              \
      yd = fmaxf(xa, fmaf(p.ad, yd, p.bd * xa));                             \
      ya = fminf(yd, fmaf(p.aa, ya, p.ba * yd));                             \
      float et = fmaxf((yd - ya) - p.nuamp, 0.0f);                           \
      ye = fmaxf(et, fmaf(p.ad, ye, p.bd * et));                             \
      oo[j] = (V)[j] * (et / (ye + p.reg));                                  \
    }                                                                        \
    __builtin_nontemporal_store(oo, &oc[OIDX]);                              \
  }
        STEP3(v0, 0) STEP3(v1, 1) STEP3(v2, 2)
        STEP3(v3, 3) STEP3(v4, 4) STEP3(v5, 5)
#undef STEP3
      }
    }
  }
}

// In-block scan over this series' FNC_ chunk summaries (Ac/Bc in LDS),
// writing per-chunk start values Y to GLOBAL ws (read by later sweeps).
template <int ATTACK>
__device__ __forceinline__ void scan_lds(const float* __restrict__ Ac,
                                         const float* __restrict__ Bc,
                                         float* __restrict__ Y,
                                         const EnvP& p,
                                         float* __restrict__ sbuf, int t) {
  constexpr int CPT = (FNC_ + FTH - 1) / FTH;   // 4
  const float alpha = ATTACK ? p.aa : p.ad;
  const float ID_A  = ATTACK ? INFINITY : -INFINITY;
  const float gS = powf(alpha, (float)FS_);

  float ca[CPT], cb[CPT];
  float a = ID_A, b = 0.0f, g = 1.0f;
#pragma unroll
  for (int k = 0; k < CPT; ++k) {
    int c = t * CPT + k;
    if (c < FNC_) { ca[k] = Ac[c]; cb[k] = Bc[c]; }
    else          { ca[k] = ID_A;  cb[k] = 0.0f; }
    float cg = (c < FNC_) ? gS : 1.0f;
    float na = ATTACK ? fminf(ca[k], fmaf(cg, a, cb[k]))
                      : fmaxf(ca[k], fmaf(cg, a, cb[k]));
    b = fmaf(cg, b, cb[k]);
    g = cg * g;
    a = na;
  }

  float* sA = sbuf; float* sB = sbuf + FTH; float* sG = sbuf + 2 * FTH;
  sA[t] = a; sB[t] = b; sG[t] = g;
  __syncthreads();
#pragma unroll
  for (int d = 1; d < FTH; d <<= 1) {
    float pa = 0.0f, pb = 0.0f, pg = 0.0f;
    if (t >= d) { pa = sA[t - d]; pb = sB[t - d]; pg = sG[t - d]; }
    __syncthreads();
    if (t >= d) {
      float na = ATTACK ? fminf(a, fmaf(g, pa, b)) : fmaxf(a, fmaf(g, pa, b));
      b = fmaf(g, pb, b);
      g = g * pg;
      a = na;
      sA[t] = a; sB[t] = b; sG[t] = g;
    }
    __syncthreads();
  }

  float ea, eb;
  if (t == 0) { ea = ID_A; eb = 0.0f; }
  else        { ea = sA[t - 1]; eb = sB[t - 1]; }

#pragma unroll
  for (int k = 0; k < CPT; ++k) {
    int c = t * CPT + k;
    if (c >= FNC_) break;
    Y[c] = ATTACK ? fminf(ea, eb) : fmaxf(ea, eb);   // eval at y0=0
    float na = ATTACK ? fminf(ca[k], fmaf(gS, ea, cb[k]))
                      : fmaxf(ca[k], fmaf(gS, ea, cb[k]));
    eb = fmaf(gS, eb, cb[k]);
    ea = na;
  }
}

// ---- the fused one-block-per-series kernel (1024 threads, 16 waves) -------
// Static LDS 41.7KB; waves_per_eu(4,4) -> 128-VGPR budget (kernel ~70, no
// spill), 4 waves/SIMD of real TLP with no intra-sweep barriers.
__global__
__attribute__((amdgpu_flat_work_group_size(1024, 1024), amdgpu_waves_per_eu(4, 4)))
void k_one(const float* __restrict__ x,
           const float* tauA, const float* tauD,
           const float* nu, const float* dbreg,
           float* __restrict__ Ydg, float* __restrict__ Yag,
           float* __restrict__ Yeg,
           float* __restrict__ out) {
  __shared__ float Ac[FNC_];                  // 14700 B
  __shared__ float Bc[FNC_];                  // 14700 B
  __shared__ float sbuf[3 * FTH];             // 12288 B  -> 41688 B total
  const int t = threadIdx.x;
  const int s = blockIdx.x;
  const float* xs = x   + (size_t)s * kT;
  float*       os = out + (size_t)s * kT;
  float* Yd = Ydg + (size_t)s * FNC_;
  float* Ya = Yag + (size_t)s * FNC_;
  float* Ye = Yeg + (size_t)s * FNC_;
  EnvP p = make_params(tauA, tauD, nu, dbreg);

  sweep<0>(xs, nullptr, p, Ac, Bc, nullptr, nullptr, nullptr, t);
  __syncthreads();
  scan_lds<0>(Ac, Bc, Yd, p, sbuf, t);
  __syncthreads();
  sweep<1>(xs, nullptr, p, Ac, Bc, Yd, nullptr, nullptr, t);
  __syncthreads();
  scan_lds<1>(Ac, Bc, Ya, p, sbuf, t);
  __syncthreads();
  sweep<2>(xs, nullptr, p, Ac, Bc, Yd, Ya, nullptr, t);
  __syncthreads();
  scan_lds<0>(Ac, Bc, Ye, p, sbuf, t);
  __syncthreads();
  sweep<3>(xs, os, p, Ac, Bc, Yd, Ya, Ye, t);
}

// ---- Fallback: the verified 235us 7-kernel pipeline -----------------------
template <int FS, int MODE>
__global__ __launch_bounds__(256)
void k_pass(const float* __restrict__ x,
            const float* tauA, const float* tauD,
            const float* nu, const float* dbreg,
            const float* __restrict__ FYd, const float* __restrict__ FYa,
            const float* __restrict__ FYe,
            float* __restrict__ O0, float* __restrict__ O1) {
  constexpr int FP = FS + 4;
  __shared__ float lds[256 * FP];
  const int t   = threadIdx.x;
  const int blk = blockIdx.x;
  const size_t tileBase = (size_t)blk * (256 * FS);
  const float4* xg = reinterpret_cast<const float4*>(x + tileBase);
#pragma unroll
  for (int i = 0; i < FS / 4; ++i) {
    int idx = t + i * 256;
    float4 v = xg[idx];
    int chunk = (idx * 4) / FS;
    int off   = idx * 4 - chunk * FS;
    *reinterpret_cast<float4*>(&lds[chunk * FP + off]) = v;
  }
  __syncthreads();
  EnvP p = make_params(tauA, tauD, nu, dbreg);
  const int gchunk = blk * 256 + t;
  float* my = &lds[t * FP];
  if (MODE == 0) {
    float A = -INFINITY, B = 0.0f;
#pragma unroll 2
    for (int i = 0; i < FS / 4; ++i) {
      float4 v = *reinterpret_cast<const float4*>(&my[4 * i]);
      float vv[4] = {v.x, v.y, v.z, v.w};
#pragma unroll
      for (int j = 0; j < 4; ++j) {
        float xa = fabsf(vv[j]);
        float bx = p.bd * xa;
        A = fmaxf(xa, fmaf(p.ad, A, bx));
        B = fmaf(p.ad, B, bx);
      }
    }
    O0[gchunk] = A; O1[gchunk] = B;
  } else if (MODE == 1) {
    float yd = FYd[gchunk];
    float A = INFINITY, B = 0.0f;
#pragma unroll 2
    for (int i = 0; i < FS / 4; ++i) {
      float4 v = *reinterpret_cast<const float4*>(&my[4 * i]);
      float vv[4] = {v.x, v.y, v.z, v.w};
#pragma unroll
      for (int j = 0; j < 4; ++j) {
        float xa = fabsf(vv[j]);
        yd = fmaxf(xa, fmaf(p.ad, yd, p.bd * xa));
        float by = p.ba * yd;
        A = fminf(yd, fmaf(p.aa, A, by));
        B = fmaf(p.aa, B, by);
      }
    }
    O0[gchunk] = A; O1[gchunk] = B;
  } else if (MODE == 2) {
    float yd = FYd[gchunk], ya = FYa[gchunk];
    float A = -INFINITY, B = 0.0f;
#pragma unroll 2
    for (int i = 0; i < FS / 4; ++i) {
      float4 v = *reinterpret_cast<const float4*>(&my[4 * i]);
      float vv[4] = {v.x, v.y, v.z, v.w};
#pragma unroll
      for (int j = 0; j < 4; ++j) {
        float xa = fabsf(vv[j]);
        yd = fmaxf(xa, fmaf(p.ad, yd, p.bd * xa));
        ya = fminf(yd, fmaf(p.aa, ya, p.ba * yd));
        float et = fmaxf((yd - ya) - p.nuamp, 0.0f);
        float bx = p.bd * et;
        A = fmaxf(et, fmaf(p.ad, A, bx));
        B = fmaf(p.ad, B, bx);
      }
    }
    O0[gchunk] = A; O1[gchunk] = B;
  } else {
    float yd = FYd[gchunk], ya = FYa[gchunk], ye = FYe[gchunk];
#pragma unroll 2
    for (int i = 0; i < FS / 4; ++i) {
      float4 v = *reinterpret_cast<const float4*>(&my[4 * i]);
      float vv[4] = {v.x, v.y, v.z, v.w};
      float oo[4];
#pragma unroll
      for (int j = 0; j < 4; ++j) {
        float xa = fabsf(vv[j]);
        yd = fmaxf(xa, fmaf(p.ad, yd, p.bd * xa));
        ya = fminf(yd, fmaf(p.aa, ya, p.ba * yd));
        float et = fmaxf((yd - ya) - p.nuamp, 0.0f);
        ye = fmaxf(et, fmaf(p.ad, ye, p.bd * et));
        oo[j] = vv[j] * (et / (ye + p.reg));
      }
      *reinterpret_cast<float4*>(&my[4 * i]) = make_float4(oo[0], oo[1], oo[2], oo[3]);
    }
    __syncthreads();
    float4* og = reinterpret_cast<float4*>(O0 + tileBase);
#pragma unroll
    for (int i = 0; i < FS / 4; ++i) {
      int idx = t + i * 256;
      int chunk = (idx * 4) / FS;
      int off   = idx * 4 - chunk * FS;
      og[idx] = *reinterpret_cast<const float4*>(&lds[chunk * FP + off]);
    }
  }
}

template <int FS, int ATTACK>
__global__ __launch_bounds__(256)
void k_scan(const float* __restrict__ A, const float* __restrict__ B,
            float* __restrict__ Y,
            const float* tauA, const float* tauD,
            const float* nu, const float* dbreg) {
  constexpr int FNC = kT / FS;
  constexpr int CPT = (FNC + 255) / 256;
  EnvP p = make_params(tauA, tauD, nu, dbreg);
  const float alpha = ATTACK ? p.aa : p.ad;
  const float ID_A  = ATTACK ? INFINITY : -INFINITY;
  int s = blockIdx.x, t = threadIdx.x;
  long base = (long)s * FNC;
  float gS = powf(alpha, (float)FS);

  float ca[CPT], cb[CPT];
  float a = ID_A, b = 0.0f, g = 1.0f;
#pragma unroll
  for (int k = 0; k < CPT; ++k) {
    int c = t * CPT + k;
    if (c < FNC) { ca[k] = A[base + c]; cb[k] = B[base + c]; }
    else         { ca[k] = ID_A;        cb[k] = 0.0f; }
    float cg = (c < FNC) ? gS : 1.0f;
    float na = ATTACK ? fminf(ca[k], fmaf(cg, a, cb[k]))
                      : fmaxf(ca[k], fmaf(cg, a, cb[k]));
    b = fmaf(cg, b, cb[k]);
    g = cg * g;
    a = na;
  }

  __shared__ float sA[256], sB[256], sG[256];
  sA[t] = a; sB[t] = b; sG[t] = g;
  __syncthreads();
#pragma unroll
  for (int d = 1; d < 256; d <<= 1) {
    float pa = 0.0f, pb = 0.0f, pg = 0.0f;
    if (t >= d) { pa = sA[t - d]; pb = sB[t - d]; pg = sG[t - d]; }
    __syncthreads();
    if (t >= d) {
      float na = ATTACK ? fminf(a, fmaf(g, pa, b)) : fmaxf(a, fmaf(g, pa, b));
      b = fmaf(g, pb, b);
      g = g * pg;
      a = na;
      sA[t] = a; sB[t] = b; sG[t] = g;
    }
    __syncthreads();
  }

  float ea, eb;
  if (t == 0) { ea = ID_A; eb = 0.0f; }
  else        { ea = sA[t - 1]; eb = sB[t - 1]; }

#pragma unroll
  for (int k = 0; k < CPT; ++k) {
    int c = t * CPT + k;
    if (c >= FNC) break;
    Y[base + c] = ATTACK ? fminf(ea, eb) : fmaxf(ea, eb);
    float na = ATTACK ? fminf(ca[k], fmaf(gS, ea, cb[k]))
                      : fmaxf(ca[k], fmaf(gS, ea, cb[k]));
    eb = fmaf(gS, eb, cb[k]);
    ea = na;
  }
}

template <int FS>
static void run_pipeline(const float* x, const float* tauA, const float* tauD,
                         const float* nu, const float* dbreg, float* out,
                         float* wsf, int nseries, hipStream_t stream) {
  const int nc  = kT / FS;
  const int nch = nseries * nc;
  float* A   = wsf;
  float* B   = wsf + (size_t)nch;
  float* FYd = wsf + (size_t)2 * nch;
  float* FYa = wsf + (size_t)3 * nch;
  float* FYe = wsf + (size_t)4 * nch;
  const int grid = nch / 256;

  k_pass<FS, 0><<<grid, 256, 0, stream>>>(x, tauA, tauD, nu, dbreg, nullptr, nullptr, nullptr, A, B);
  k_scan<FS, 0><<<nseries, 256, 0, stream>>>(A, B, FYd, tauA, tauD, nu, dbreg);
  k_pass<FS, 1><<<grid, 256, 0, stream>>>(x, tauA, tauD, nu, dbreg, FYd, nullptr, nullptr, A, B);
  k_scan<FS, 1><<<nseries, 256, 0, stream>>>(A, B, FYa, tauA, tauD, nu, dbreg);
  k_pass<FS, 2><<<grid, 256, 0, stream>>>(x, tauA, tauD, nu, dbreg, FYd, FYa, nullptr, A, B);
  k_scan<FS, 0><<<nseries, 256, 0, stream>>>(A, B, FYe, tauA, tauD, nu, dbreg);
  k_pass<FS, 3><<<grid, 256, 0, stream>>>(x, tauA, tauD, nu, dbreg, FYd, FYa, FYe, out, nullptr);
}

extern "C" void kernel_launch(void* const* d_in, const int* in_sizes, int n_in,
                              void* d_out, int out_size, void* d_ws, size_t ws_size,
                              hipStream_t stream) {
  const float* x     = (const float*)d_in[0];
  const float* tauA  = (const float*)d_in[1];
  const float* tauD  = (const float*)d_in[2];
  const float* nu    = (const float*)d_in[3];
  const float* dbreg = (const float*)d_in[4];
  float* out = (float*)d_out;
  float* wsf = (float*)d_ws;
  const int nseries = in_sizes[0] / kT;       // 256

  const size_t NS = (size_t)FNC_ * nseries;   // floats per Y array
  const bool wsOK = 3 * NS * sizeof(float) <= ws_size;  // 11,289,600 B

  if (wsOK) {
    float* Yd = wsf;
    float* Ya = wsf + NS;
    float* Ye = wsf + 2 * NS;
    k_one<<<nseries, FTH, 0, stream>>>(x, tauA, tauD, nu, dbreg, Yd, Ya, Ye, out);
    return;
  }

  auto fits = [&](int FS) {
    return (size_t)5 * nseries * (kT / FS) * sizeof(float) <= ws_size;
  };
  if      (fits(40))  run_pipeline<40 >(x, tauA, tauD, nu, dbreg, out, wsf, nseries, stream);
  else if (fits(56))  run_pipeline<56 >(x, tauA, tauD, nu, dbreg, out, wsf, nseries, stream);
  else if (fits(72))  run_pipeline<72 >(x, tauA, tauD, nu, dbreg, out, wsf, nseries, stream);
  else                run_pipeline<120>(x, tauA, tauD, nu, dbreg, out, wsf, nseries, stream);
}

// Round 8
// 224.473 us; speedup vs baseline: 1.7827x; 1.7827x over previous
//
#include <hip/hip_runtime.h>
#include <cmath>

// Temporal Contrast Enhancement — R11: R5 structure + 2-chunk ILP per thread.
// R7 post-mortem: direct per-thread chunk loads = 96B-stride lane scatter ->
// partial-line write amplification (WRITE 2.4x), 19% HBM, 12% VALU. Staging
// transpose is mandatory. R5 (106us) analysis: at 1 wave/SIMD the recurrence
// dep-chain (~8cyc/elem) and ds_read_b128 latency (~120cyc) have nothing to
// overlap -> VALUBusy 32%. Fix: each thread processes TWO independent chunks
// per tile (tile = 512 chunks in ONE 90KB LDS buffer; next tile prefetched
// into 20 named f32x4 regs; staging addresses hoisted to 20 named ints).
// Two independent chains + two ds_read streams fill both latency types.

typedef float f32x4 __attribute__((ext_vector_type(4)));

static constexpr int   kT  = 88200;
static constexpr float kSR = 44100.0f;

static constexpr int S        = 40;                 // chunk length
static constexpr int NC       = kT / S;             // 2205 chunks/series
static constexpr int PADS     = S + 4;              // padded LDS chunk stride
static constexpr int TCH      = 512;                // chunks per tile (2/thread)
static constexpr int NT       = (NC + TCH - 1) / TCH;   // 5 tiles
static constexpr int F4C      = S / 4;              // 10 float4 per chunk
static constexpr int TILE_F4  = TCH * F4C;          // 5120 float4 per full tile
static constexpr int TAIL_F4  = (NC - TCH * (NT - 1)) * F4C;  // 157*10 = 1570
static constexpr int BUF_F    = TCH * PADS;         // 22528 floats (90112 B)

struct EnvP { float ad, bd, aa, ba, nuamp, reg; };

__device__ __forceinline__ EnvP make_params(const float* tauA, const float* tauD,
                                            const float* nu, const float* dbreg) {
  EnvP p;
  float td = fminf(fmaxf(tauD[0], 1.0f), 100.0f);
  td = fminf(fmaxf(td, 0.1f), 1000.0f) * 0.001f;
  float ta = fminf(fmaxf(tauA[0], 1.0f), 100.0f);
  ta = fminf(fmaxf(ta, 0.1f), 1000.0f) * 0.001f;
  p.ad = expf(-1.0f / (td * kSR));
  p.aa = expf(-1.0f / (ta * kSR));
  p.bd = 1.0f - p.ad;
  p.ba = 1.0f - p.aa;
  p.nuamp = exp10f(fminf(fmaxf(nu[0],    -60.0f),   0.0f) * 0.05f);
  p.reg   = exp10f(fminf(fmaxf(dbreg[0], -120.0f), -60.0f) * 0.05f);
  return p;
}

#define REPEAT20(M) M(0) M(1) M(2) M(3) M(4) M(5) M(6) M(7) M(8) M(9) \
                    M(10) M(11) M(12) M(13) M(14) M(15) M(16) M(17) M(18) M(19)

// MODE: 0=comp_d  1=comp_a(replay yd)  2=comp_e(replay yd,ya)  3=final
template <int MODE>
__device__ __forceinline__ void sweep(const float* __restrict__ xs,
                                      float* __restrict__ os,
                                      const EnvP& p,
                                      float* __restrict__ buf,
                                      float* __restrict__ Ac, float* __restrict__ Bc,
                                      const float* __restrict__ Ydl,
                                      const float* __restrict__ Yal,
                                      const float* __restrict__ Yel,
                                      int t) {
  // 20 NAMED staging registers + 20 NAMED hoisted LDS addresses (float idx).
#define DECL_R(K) f32x4 r##K;
  REPEAT20(DECL_R)
#undef DECL_R
#define DECL_A(K) const int a##K = ((t + K * 256) / F4C) * PADS \
                                   + ((t + K * 256) % F4C) * 4;
  REPEAT20(DECL_A)
#undef DECL_A
  const f32x4* xg4 = reinterpret_cast<const f32x4*>(xs);

#define LD1(K) { int i_ = t + K * 256; r##K = xg_[i_ < nf4_ ? i_ : 0]; }
#define LD_TILE(TILE)                                                        \
  do {                                                                       \
    const int nf4_ = ((TILE) == NT - 1) ? TAIL_F4 : TILE_F4;                 \
    const f32x4* xg_ = xg4 + (size_t)(TILE) * TILE_F4;                       \
    REPEAT20(LD1)                                                            \
  } while (0)

#define WR1(K) *reinterpret_cast<f32x4*>(buf + a##K) = r##K;
#define WR_TILE() do { REPEAT20(WR1) } while (0)

  LD_TILE(0);
  WR_TILE();
  __syncthreads();

  for (int it = 0; it < NT; ++it) {
    const bool pf = (it + 1 < NT);
    if (pf) LD_TILE(it + 1);                  // issue next-tile loads NOW
    __builtin_amdgcn_sched_barrier(0);        // pin issue before compute

    const int g0 = it * TCH + t;              // this thread's two chunks
    const int g1 = g0 + 256;
    const int g0c = g0 < NC ? g0 : NC - 1;    // clamped (LDS-safe) indices
    const int g1c = g1 < NC ? g1 : NC - 1;
    const float* my0 = buf + t * PADS;
    float* my1 = buf + (t + 256) * PADS;
    float* my0w = buf + t * PADS;

    if (MODE == 0) {
      float A0 = -INFINITY, B0 = 0.0f, A1 = -INFINITY, B1 = 0.0f;
#pragma unroll
      for (int i = 0; i < F4C; ++i) {
        f32x4 v0 = *reinterpret_cast<const f32x4*>(my0 + 4 * i);
        f32x4 v1 = *reinterpret_cast<const f32x4*>(my1 + 4 * i);
#pragma unroll
        for (int j = 0; j < 4; ++j) {
          float xa0 = fabsf(v0[j]);
          float xa1 = fabsf(v1[j]);
          float bx0 = p.bd * xa0, bx1 = p.bd * xa1;
          A0 = fmaxf(xa0, fmaf(p.ad, A0, bx0));
          A1 = fmaxf(xa1, fmaf(p.ad, A1, bx1));
          B0 = fmaf(p.ad, B0, bx0);
          B1 = fmaf(p.ad, B1, bx1);
        }
      }
      if (g0 < NC) { Ac[g0] = A0; Bc[g0] = B0; }
      if (g1 < NC) { Ac[g1] = A1; Bc[g1] = B1; }
    } else if (MODE == 1) {
      float yd0 = Ydl[g0c], yd1 = Ydl[g1c];
      float A0 = INFINITY, B0 = 0.0f, A1 = INFINITY, B1 = 0.0f;
#pragma unroll
      for (int i = 0; i < F4C; ++i) {
        f32x4 v0 = *reinterpret_cast<const f32x4*>(my0 + 4 * i);
        f32x4 v1 = *reinterpret_cast<const f32x4*>(my1 + 4 * i);
#pragma unroll
        for (int j = 0; j < 4; ++j) {
          float xa0 = fabsf(v0[j]);
          float xa1 = fabsf(v1[j]);
          yd0 = fmaxf(xa0, fmaf(p.ad, yd0, p.bd * xa0));
          yd1 = fmaxf(xa1, fmaf(p.ad, yd1, p.bd * xa1));
          float by0 = p.ba * yd0, by1 = p.ba * yd1;
          A0 = fminf(yd0, fmaf(p.aa, A0, by0));
          A1 = fminf(yd1, fmaf(p.aa, A1, by1));
          B0 = fmaf(p.aa, B0, by0);
          B1 = fmaf(p.aa, B1, by1);
        }
      }
      if (g0 < NC) { Ac[g0] = A0; Bc[g0] = B0; }
      if (g1 < NC) { Ac[g1] = A1; Bc[g1] = B1; }
    } else if (MODE == 2) {
      float yd0 = Ydl[g0c], ya0 = Yal[g0c];
      float yd1 = Ydl[g1c], ya1 = Yal[g1c];
      float A0 = -INFINITY, B0 = 0.0f, A1 = -INFINITY, B1 = 0.0f;
#pragma unroll
      for (int i = 0; i < F4C; ++i) {
        f32x4 v0 = *reinterpret_cast<const f32x4*>(my0 + 4 * i);
        f32x4 v1 = *reinterpret_cast<const f32x4*>(my1 + 4 * i);
#pragma unroll
        for (int j = 0; j < 4; ++j) {
          float xa0 = fabsf(v0[j]);
          float xa1 = fabsf(v1[j]);
          yd0 = fmaxf(xa0, fmaf(p.ad, yd0, p.bd * xa0));
          yd1 = fmaxf(xa1, fmaf(p.ad, yd1, p.bd * xa1));
          ya0 = fminf(yd0, fmaf(p.aa, ya0, p.ba * yd0));
          ya1 = fminf(yd1, fmaf(p.aa, ya1, p.ba * yd1));
          float et0 = fmaxf((yd0 - ya0) - p.nuamp, 0.0f);
          float et1 = fmaxf((yd1 - ya1) - p.nuamp, 0.0f);
          float bx0 = p.bd * et0, bx1 = p.bd * et1;
          A0 = fmaxf(et0, fmaf(p.ad, A0, bx0));
          A1 = fmaxf(et1, fmaf(p.ad, A1, bx1));
          B0 = fmaf(p.ad, B0, bx0);
          B1 = fmaf(p.ad, B1, bx1);
        }
      }
      if (g0 < NC) { Ac[g0] = A0; Bc[g0] = B0; }
      if (g1 < NC) { Ac[g1] = A1; Bc[g1] = B1; }
    } else {
      float yd0 = Ydl[g0c], ya0 = Yal[g0c], ye0 = Yel[g0c];
      float yd1 = Ydl[g1c], ya1 = Yal[g1c], ye1 = Yel[g1c];
#pragma unroll
      for (int i = 0; i < F4C; ++i) {
        f32x4 v0 = *reinterpret_cast<const f32x4*>(my0 + 4 * i);
        f32x4 v1 = *reinterpret_cast<const f32x4*>(my1 + 4 * i);
        f32x4 o0, o1;
#pragma unroll
        for (int j = 0; j < 4; ++j) {
          float xa0 = fabsf(v0[j]);
          float xa1 = fabsf(v1[j]);
          yd0 = fmaxf(xa0, fmaf(p.ad, yd0, p.bd * xa0));
          yd1 = fmaxf(xa1, fmaf(p.ad, yd1, p.bd * xa1));
          ya0 = fminf(yd0, fmaf(p.aa, ya0, p.ba * yd0));
          ya1 = fminf(yd1, fmaf(p.aa, ya1, p.ba * yd1));
          float et0 = fmaxf((yd0 - ya0) - p.nuamp, 0.0f);
          float et1 = fmaxf((yd1 - ya1) - p.nuamp, 0.0f);
          ye0 = fmaxf(et0, fmaf(p.ad, ye0, p.bd * et0));
          ye1 = fmaxf(et1, fmaf(p.ad, ye1, p.bd * et1));
          o0[j] = v0[j] * (et0 / (ye0 + p.reg));
          o1[j] = v1[j] * (et1 / (ye1 + p.reg));
        }
        *reinterpret_cast<f32x4*>(my0w + 4 * i) = o0;
        *reinterpret_cast<f32x4*>(my1  + 4 * i) = o1;
      }
    }

    __syncthreads();                          // compute done; buf stable
    if (MODE == 3) {
      // coalesced out-store: reads own aK slots (transpose), nontemporal.
      f32x4* og_ = reinterpret_cast<f32x4*>(os) + (size_t)it * TILE_F4;
      const int nf4o_ = pf ? TILE_F4 : TAIL_F4;
#define ST1(K) { int i_ = t + K * 256;                                        \
                 if (i_ < nf4o_)                                              \
                   __builtin_nontemporal_store(                               \
                     *reinterpret_cast<const f32x4*>(buf + a##K), &og_[i_]); }
      REPEAT20(ST1)
#undef ST1
    }
    if (pf) WR_TILE();                        // vmcnt waits land here
    __syncthreads();
  }
#undef LD1
#undef LD_TILE
#undef WR1
#undef WR_TILE
}

// In-block scan over this series' NC chunk summaries (all LDS-resident).
template <int ATTACK>
__device__ __forceinline__ void scan_lds(const float* __restrict__ Ac,
                                         const float* __restrict__ Bc,
                                         float* __restrict__ Y,
                                         const EnvP& p,
                                         float* __restrict__ sbuf, int t) {
  constexpr int CPT = (NC + 255) / 256;       // 9
  const float alpha = ATTACK ? p.aa : p.ad;
  const float ID_A  = ATTACK ? INFINITY : -INFINITY;
  const float gS = powf(alpha, (float)S);

  float ca[CPT], cb[CPT];
  float a = ID_A, b = 0.0f, g = 1.0f;
#pragma unroll
  for (int k = 0; k < CPT; ++k) {
    int c = t * CPT + k;
    if (c < NC) { ca[k] = Ac[c]; cb[k] = Bc[c]; }
    else        { ca[k] = ID_A;  cb[k] = 0.0f; }
    float cg = (c < NC) ? gS : 1.0f;
    float na = ATTACK ? fminf(ca[k], fmaf(cg, a, cb[k]))
                      : fmaxf(ca[k], fmaf(cg, a, cb[k]));
    b = fmaf(cg, b, cb[k]);
    g = cg * g;
    a = na;
  }

  float* sA = sbuf; float* sB = sbuf + 256; float* sG = sbuf + 512;
  sA[t] = a; sB[t] = b; sG[t] = g;
  __syncthreads();
#pragma unroll
  for (int d = 1; d < 256; d <<= 1) {
    float pa = 0.0f, pb = 0.0f, pg = 0.0f;
    if (t >= d) { pa = sA[t - d]; pb = sB[t - d]; pg = sG[t - d]; }
    __syncthreads();
    if (t >= d) {
      float na = ATTACK ? fminf(a, fmaf(g, pa, b)) : fmaxf(a, fmaf(g, pa, b));
      b = fmaf(g, pb, b);
      g = g * pg;
      a = na;
      sA[t] = a; sB[t] = b; sG[t] = g;
    }
    __syncthreads();
  }

  float ea, eb;
  if (t == 0) { ea = ID_A; eb = 0.0f; }
  else        { ea = sA[t - 1]; eb = sB[t - 1]; }

#pragma unroll
  for (int k = 0; k < CPT; ++k) {
    int c = t * CPT + k;
    if (c >= NC) break;
    Y[c] = ATTACK ? fminf(ea, eb) : fmaxf(ea, eb);   // eval at y0=0
    float na = ATTACK ? fminf(ca[k], fmaf(gS, ea, cb[k]))
                      : fmaxf(ca[k], fmaf(gS, ea, cb[k]));
    eb = fmaf(gS, eb, cb[k]);
    ea = na;
  }
}

// ---- the fused one-block-per-series kernel --------------------------------
// 134KB dynamic LDS -> 1 block/CU; waves_per_eu(1,1) -> full VGPR budget so
// the 20 named staging regs + two chain states stay resident (no scratch).
__global__
__attribute__((amdgpu_flat_work_group_size(256, 256), amdgpu_waves_per_eu(1, 1)))
void k_one(const float* __restrict__ x,
           const float* tauA, const float* tauD,
           const float* nu, const float* dbreg,
           float* __restrict__ out) {
  extern __shared__ float lds[];
  float* buf = lds;                           // 22528 f (90112 B)
  float* Ac  = lds + BUF_F;                   // 2205 f
  float* Bc  = Ac + NC;                       // 2205 f
  float* Yd  = Bc + NC;                       // 2205 f
  float* Ya  = Yd + NC;                       // 2205 f
  float* Ye  = Ya + NC;                       // 2205 f  -> total 134212 B
  const int t = threadIdx.x;
  const float* xs = x   + (size_t)blockIdx.x * kT;
  float*       os = out + (size_t)blockIdx.x * kT;
  EnvP p = make_params(tauA, tauD, nu, dbreg);

  sweep<0>(xs, nullptr, p, buf, Ac, Bc, nullptr, nullptr, nullptr, t);
  scan_lds<0>(Ac, Bc, Yd, p, buf, t);         // buf free between sweeps
  __syncthreads();
  sweep<1>(xs, nullptr, p, buf, Ac, Bc, Yd, nullptr, nullptr, t);
  scan_lds<1>(Ac, Bc, Ya, p, buf, t);
  __syncthreads();
  sweep<2>(xs, nullptr, p, buf, Ac, Bc, Yd, Ya, nullptr, t);
  scan_lds<0>(Ac, Bc, Ye, p, buf, t);
  __syncthreads();
  sweep<3>(xs, os, p, buf, Ac, Bc, Yd, Ya, Ye, t);
}

// ---- Fallback: the verified 235us 7-kernel pipeline -----------------------
template <int FS, int MODE>
__global__ __launch_bounds__(256)
void k_pass(const float* __restrict__ x,
            const float* tauA, const float* tauD,
            const float* nu, const float* dbreg,
            const float* __restrict__ FYd, const float* __restrict__ FYa,
            const float* __restrict__ FYe,
            float* __restrict__ O0, float* __restrict__ O1) {
  constexpr int FP = FS + 4;
  __shared__ float lds[256 * FP];
  const int t   = threadIdx.x;
  const int blk = blockIdx.x;
  const size_t tileBase = (size_t)blk * (256 * FS);
  const float4* xg = reinterpret_cast<const float4*>(x + tileBase);
#pragma unroll
  for (int i = 0; i < FS / 4; ++i) {
    int idx = t + i * 256;
    float4 v = xg[idx];
    int chunk = (idx * 4) / FS;
    int off   = idx * 4 - chunk * FS;
    *reinterpret_cast<float4*>(&lds[chunk * FP + off]) = v;
  }
  __syncthreads();
  EnvP p = make_params(tauA, tauD, nu, dbreg);
  const int gchunk = blk * 256 + t;
  float* my = &lds[t * FP];
  if (MODE == 0) {
    float A = -INFINITY, B = 0.0f;
#pragma unroll 2
    for (int i = 0; i < FS / 4; ++i) {
      float4 v = *reinterpret_cast<const float4*>(&my[4 * i]);
      float vv[4] = {v.x, v.y, v.z, v.w};
#pragma unroll
      for (int j = 0; j < 4; ++j) {
        float xa = fabsf(vv[j]);
        float bx = p.bd * xa;
        A = fmaxf(xa, fmaf(p.ad, A, bx));
        B = fmaf(p.ad, B, bx);
      }
    }
    O0[gchunk] = A; O1[gchunk] = B;
  } else if (MODE == 1) {
    float yd = FYd[gchunk];
    float A = INFINITY, B = 0.0f;
#pragma unroll 2
    for (int i = 0; i < FS / 4; ++i) {
      float4 v = *reinterpret_cast<const float4*>(&my[4 * i]);
      float vv[4] = {v.x, v.y, v.z, v.w};
#pragma unroll
      for (int j = 0; j < 4; ++j) {
        float xa = fabsf(vv[j]);
        yd = fmaxf(xa, fmaf(p.ad, yd, p.bd * xa));
        float by = p.ba * yd;
        A = fminf(yd, fmaf(p.aa, A, by));
        B = fmaf(p.aa, B, by);
      }
    }
    O0[gchunk] = A; O1[gchunk] = B;
  } else if (MODE == 2) {
    float yd = FYd[gchunk], ya = FYa[gchunk];
    float A = -INFINITY, B = 0.0f;
#pragma unroll 2
    for (int i = 0; i < FS / 4; ++i) {
      float4 v = *reinterpret_cast<const float4*>(&my[4 * i]);
      float vv[4] = {v.x, v.y, v.z, v.w};
#pragma unroll
      for (int j = 0; j < 4; ++j) {
        float xa = fabsf(vv[j]);
        yd = fmaxf(xa, fmaf(p.ad, yd, p.bd * xa));
        ya = fminf(yd, fmaf(p.aa, ya, p.ba * yd));
        float et = fmaxf((yd - ya) - p.nuamp, 0.0f);
        float bx = p.bd * et;
        A = fmaxf(et, fmaf(p.ad, A, bx));
        B = fmaf(p.ad, B, bx);
      }
    }
    O0[gchunk] = A; O1[gchunk] = B;
  } else {
    float yd = FYd[gchunk], ya = FYa[gchunk], ye = FYe[gchunk];
#pragma unroll 2
    for (int i = 0; i < FS / 4; ++i) {
      float4 v = *reinterpret_cast<const float4*>(&my[4 * i]);
      float vv[4] = {v.x, v.y, v.z, v.w};
      float oo[4];
#pragma unroll
      for (int j = 0; j < 4; ++j) {
        float xa = fabsf(vv[j]);
        yd = fmaxf(xa, fmaf(p.ad, yd, p.bd * xa));
        ya = fminf(yd, fmaf(p.aa, ya, p.ba * yd));
        float et = fmaxf((yd - ya) - p.nuamp, 0.0f);
        ye = fmaxf(et, fmaf(p.ad, ye, p.bd * et));
        oo[j] = vv[j] * (et / (ye + p.reg));
      }
      *reinterpret_cast<float4*>(&my[4 * i]) = make_float4(oo[0], oo[1], oo[2], oo[3]);
    }
    __syncthreads();
    float4* og = reinterpret_cast<float4*>(O0 + tileBase);
#pragma unroll
    for (int i = 0; i < FS / 4; ++i) {
      int idx = t + i * 256;
      int chunk = (idx * 4) / FS;
      int off   = idx * 4 - chunk * FS;
      og[idx] = *reinterpret_cast<const float4*>(&lds[chunk * FP + off]);
    }
  }
}

template <int FS, int ATTACK>
__global__ __launch_bounds__(256)
void k_scan(const float* __restrict__ A, const float* __restrict__ B,
            float* __restrict__ Y,
            const float* tauA, const float* tauD,
            const float* nu, const float* dbreg) {
  constexpr int FNC = kT / FS;
  constexpr int CPT = (FNC + 255) / 256;
  EnvP p = make_params(tauA, tauD, nu, dbreg);
  const float alpha = ATTACK ? p.aa : p.ad;
  const float ID_A  = ATTACK ? INFINITY : -INFINITY;
  int s = blockIdx.x, t = threadIdx.x;
  long base = (long)s * FNC;
  float gS = powf(alpha, (float)FS);

  float ca[CPT], cb[CPT];
  float a = ID_A, b = 0.0f, g = 1.0f;
#pragma unroll
  for (int k = 0; k < CPT; ++k) {
    int c = t * CPT + k;
    if (c < FNC) { ca[k] = A[base + c]; cb[k] = B[base + c]; }
    else         { ca[k] = ID_A;        cb[k] = 0.0f; }
    float cg = (c < FNC) ? gS : 1.0f;
    float na = ATTACK ? fminf(ca[k], fmaf(cg, a, cb[k]))
                      : fmaxf(ca[k], fmaf(cg, a, cb[k]));
    b = fmaf(cg, b, cb[k]);
    g = cg * g;
    a = na;
  }

  __shared__ float sA[256], sB[256], sG[256];
  sA[t] = a; sB[t] = b; sG[t] = g;
  __syncthreads();
#pragma unroll
  for (int d = 1; d < 256; d <<= 1) {
    float pa = 0.0f, pb = 0.0f, pg = 0.0f;
    if (t >= d) { pa = sA[t - d]; pb = sB[t - d]; pg = sG[t - d]; }
    __syncthreads();
    if (t >= d) {
      float na = ATTACK ? fminf(a, fmaf(g, pa, b)) : fmaxf(a, fmaf(g, pa, b));
      b = fmaf(g, pb, b);
      g = g * pg;
      a = na;
      sA[t] = a; sB[t] = b; sG[t] = g;
    }
    __syncthreads();
  }

  float ea, eb;
  if (t == 0) { ea = ID_A; eb = 0.0f; }
  else        { ea = sA[t - 1]; eb = sB[t - 1]; }

#pragma unroll
  for (int k = 0; k < CPT; ++k) {
    int c = t * CPT + k;
    if (c >= FNC) break;
    Y[base + c] = ATTACK ? fminf(ea, eb) : fmaxf(ea, eb);
    float na = ATTACK ? fminf(ca[k], fmaf(gS, ea, cb[k]))
                      : fmaxf(ca[k], fmaf(gS, ea, cb[k]));
    eb = fmaf(gS, eb, cb[k]);
    ea = na;
  }
}

template <int FS>
static void run_pipeline(const float* x, const float* tauA, const float* tauD,
                         const float* nu, const float* dbreg, float* out,
                         float* wsf, int nseries, hipStream_t stream) {
  const int nc  = kT / FS;
  const int nch = nseries * nc;
  float* A   = wsf;
  float* B   = wsf + (size_t)nch;
  float* FYd = wsf + (size_t)2 * nch;
  float* FYa = wsf + (size_t)3 * nch;
  float* FYe = wsf + (size_t)4 * nch;
  const int grid = nch / 256;

  k_pass<FS, 0><<<grid, 256, 0, stream>>>(x, tauA, tauD, nu, dbreg, nullptr, nullptr, nullptr, A, B);
  k_scan<FS, 0><<<nseries, 256, 0, stream>>>(A, B, FYd, tauA, tauD, nu, dbreg);
  k_pass<FS, 1><<<grid, 256, 0, stream>>>(x, tauA, tauD, nu, dbreg, FYd, nullptr, nullptr, A, B);
  k_scan<FS, 1><<<nseries, 256, 0, stream>>>(A, B, FYa, tauA, tauD, nu, dbreg);
  k_pass<FS, 2><<<grid, 256, 0, stream>>>(x, tauA, tauD, nu, dbreg, FYd, FYa, nullptr, A, B);
  k_scan<FS, 0><<<nseries, 256, 0, stream>>>(A, B, FYe, tauA, tauD, nu, dbreg);
  k_pass<FS, 3><<<grid, 256, 0, stream>>>(x, tauA, tauD, nu, dbreg, FYd, FYa, FYe, out, nullptr);
}

extern "C" void kernel_launch(void* const* d_in, const int* in_sizes, int n_in,
                              void* d_out, int out_size, void* d_ws, size_t ws_size,
                              hipStream_t stream) {
  const float* x     = (const float*)d_in[0];
  const float* tauA  = (const float*)d_in[1];
  const float* tauD  = (const float*)d_in[2];
  const float* nu    = (const float*)d_in[3];
  const float* dbreg = (const float*)d_in[4];
  float* out = (float*)d_out;
  float* wsf = (float*)d_ws;
  const int nseries = in_sizes[0] / kT;       // 256

  constexpr size_t LDSZ = (size_t)(BUF_F + 5 * NC) * sizeof(float); // 134212 B

  static int fusedOK = -1;                    // one-time host-side probe
  if (fusedOK < 0) {
    hipFuncSetAttribute(reinterpret_cast<const void*>(&k_one),
                        hipFuncAttributeMaxDynamicSharedMemorySize, (int)LDSZ);
    (void)hipGetLastError();                  // clear any error state
    fusedOK = 1;
  }

  if (fusedOK == 1) {
    k_one<<<nseries, 256, LDSZ, stream>>>(x, tauA, tauD, nu, dbreg, out);
    if (hipGetLastError() == hipSuccess) return;
    fusedOK = 0;                              // launch rejected -> pipeline forever
  }

  auto fits = [&](int FS) {
    return (size_t)5 * nseries * (kT / FS) * sizeof(float) <= ws_size;
  };
  if      (fits(40))  run_pipeline<40 >(x, tauA, tauD, nu, dbreg, out, wsf, nseries, stream);
  else if (fits(56))  run_pipeline<56 >(x, tauA, tauD, nu, dbreg, out, wsf, nseries, stream);
  else if (fits(72))  run_pipeline<72 >(x, tauA, tauD, nu, dbreg, out, wsf, nseries, stream);
  else                run_pipeline<120>(x, tauA, tauD, nu, dbreg, out, wsf, nseries, stream);
}

// Round 9
// 213.872 us; speedup vs baseline: 1.8711x; 1.0496x over previous
//
#include <hip/hip_runtime.h>
#include <cmath>

// Temporal Contrast Enhancement — R12: segment-sequential single-read fusion.
// R8 post-mortem: 1-wave, 2-wave, and 2-chunk-ILP variants all converge to
// ~110us at 33% VALU; per-sweep effective BW pins at ~3.4 TB/s even in the
// 12-wave pipeline -> TRAFFIC-bound: x is read 4x (451MB logical) and L3
// re-read service is ~3.5 TB/s. Fix: the inter-segment dependency of each
// envelope is ONE SCALAR (env value at the segment boundary). Process the
// series as 9 LDS-resident segments SEQUENTIALLY: per segment, run all 4
// modes from the same 45KB LDS tile (per-mode 256-chunk scan with scalar
// carry-in via shuffle-scan), store out, advance. x read ONCE, out written
// once = 180MB total. Next segment register-prefetched (proven 10-named-reg
// pattern) under the current segment's 4 compute modes. No workspace.

typedef float f32x4 __attribute__((ext_vector_type(4)));

static constexpr int   kT  = 88200;
static constexpr float kSR = 44100.0f;

static constexpr int S       = 40;                  // chunk length
static constexpr int NC      = kT / S;              // 2205 chunks/series
static constexpr int PADS    = S + 4;               // padded LDS chunk stride
static constexpr int CHT     = 256;                 // chunks per segment
static constexpr int NSEG    = (NC + CHT - 1) / CHT;    // 9 segments
static constexpr int TAILC   = NC - CHT * (NSEG - 1);   // 157
static constexpr int F4C     = S / 4;               // 10 float4 per chunk
static constexpr int TILE_F4 = CHT * F4C;           // 2560 float4 per segment
static constexpr int TAIL_F4 = TAILC * F4C;         // 1570
static constexpr int BUF_F   = CHT * PADS;          // 11264 floats (45056 B)

struct EnvP { float ad, bd, aa, ba, nuamp, reg; };

__device__ __forceinline__ EnvP make_params(const float* tauA, const float* tauD,
                                            const float* nu, const float* dbreg) {
  EnvP p;
  float td = fminf(fmaxf(tauD[0], 1.0f), 100.0f);
  td = fminf(fmaxf(td, 0.1f), 1000.0f) * 0.001f;
  float ta = fminf(fmaxf(tauA[0], 1.0f), 100.0f);
  ta = fminf(fmaxf(ta, 0.1f), 1000.0f) * 0.001f;
  p.ad = expf(-1.0f / (td * kSR));
  p.aa = expf(-1.0f / (ta * kSR));
  p.bd = 1.0f - p.ad;
  p.ba = 1.0f - p.aa;
  p.nuamp = exp10f(fminf(fmaxf(nu[0],    -60.0f),   0.0f) * 0.05f);
  p.reg   = exp10f(fminf(fmaxf(dbreg[0], -120.0f), -60.0f) * 0.05f);
  return p;
}

// Segment-level scan of chunk maps f(y) = op(A, G*y + B) with scalar carry.
// Returns this thread's chunk-init value; thread 0 updates the carry slot.
// wA/wB/wG: 4-entry wave-total arrays (per mode, no cross-scan reuse race).
// carry2: double-buffered {read [g&1], write [(g+1)&1]}.
template <int ATTACK>
__device__ __forceinline__ float seg_scan(float a, float b, bool valid,
                                          const float gS,
                                          volatile float* wA, volatile float* wB,
                                          volatile float* wG,
                                          float* carry2, int g, int t) {
  const float ID_A = ATTACK ? INFINITY : -INFINITY;
  float gg = gS;
  if (!valid) { a = ID_A; b = 0.0f; gg = 1.0f; }
  const int lane = t & 63, wid = t >> 6;
  // intra-wave inclusive scan (Hillis-Steele), no barriers
#pragma unroll
  for (int d = 1; d < 64; d <<= 1) {
    float pa = __shfl_up(a, d), pb = __shfl_up(b, d), pg = __shfl_up(gg, d);
    if (lane >= d) {
      float na = ATTACK ? fminf(a, fmaf(gg, pa, b)) : fmaxf(a, fmaf(gg, pa, b));
      b  = fmaf(gg, pb, b);
      gg = gg * pg;
      a  = na;
    }
  }
  if (lane == 63) { wA[wid] = a; wB[wid] = b; wG[wid] = gg; }
  __syncthreads();
  const float cin = carry2[g & 1];
  // wave prefix P = totals of waves [0, wid)
  float Pa = ID_A, Pb = 0.0f, Pg = 1.0f;
#pragma unroll
  for (int w = 0; w < 3; ++w) {
    if (w < wid) {
      float ca = wA[w], cb = wB[w], cg = wG[w];
      float na = ATTACK ? fminf(ca, fmaf(cg, Pa, cb)) : fmaxf(ca, fmaf(cg, Pa, cb));
      Pb = fmaf(cg, Pb, cb);
      Pg = cg * Pg;
      Pa = na;
    }
  }
  // exclusive-in-wave
  float xa = __shfl_up(a, 1), xb = __shfl_up(b, 1), xg = __shfl_up(gg, 1);
  if (lane == 0) { xa = ID_A; xb = 0.0f; xg = 1.0f; }
  // E = excl ∘ P  (map over chunks [segment start, this chunk))
  float Ea = ATTACK ? fminf(xa, fmaf(xg, Pa, xb)) : fmaxf(xa, fmaf(xg, Pa, xb));
  float Eb = fmaf(xg, Pb, xb);
  float Eg = xg * Pg;
  float init = ATTACK ? fminf(Ea, fmaf(Eg, cin, Eb)) : fmaxf(Ea, fmaf(Eg, cin, Eb));
  // segment-total map F -> carry' (written to the OTHER slot; no race)
  if (t == 0) {
    float Fa = ID_A, Fb = 0.0f, Fg = 1.0f;
#pragma unroll
    for (int w = 0; w < 4; ++w) {
      float ca = wA[w], cb = wB[w], cg = wG[w];
      float na = ATTACK ? fminf(ca, fmaf(cg, Fa, cb)) : fmaxf(ca, fmaf(cg, Fa, cb));
      Fb = fmaf(cg, Fb, cb);
      Fg = cg * Fg;
      Fa = na;
    }
    carry2[(g + 1) & 1] = ATTACK ? fminf(Fa, fmaf(Fg, cin, Fb))
                                 : fmaxf(Fa, fmaf(Fg, cin, Fb));
  }
  return init;
}

#define REPEAT10(M) M(0) M(1) M(2) M(3) M(4) M(5) M(6) M(7) M(8) M(9)

// ---- the fused one-block-per-series kernel --------------------------------
// 45KB static LDS; 256 threads (4 waves). waves_per_eu(1,1): grid=256 gives
// 1 block/CU anyway; full VGPR budget keeps the 10 named prefetch regs and
// the recurrence state resident (no scratch — proven R5 pattern).
__global__
__attribute__((amdgpu_flat_work_group_size(256, 256), amdgpu_waves_per_eu(1, 1)))
void k_one(const float* __restrict__ x,
           const float* tauA, const float* tauD,
           const float* nu, const float* dbreg,
           float* __restrict__ out) {
  __shared__ float buf[BUF_F];                // 45056 B
  __shared__ float wAm[3][4], wBm[3][4], wGm[3][4];
  __shared__ float carry[3][2];               // [mode][g&1]
  const int t = threadIdx.x;
  const float* xs = x   + (size_t)blockIdx.x * kT;
  float*       os = out + (size_t)blockIdx.x * kT;
  EnvP p = make_params(tauA, tauD, nu, dbreg);
  const float gSd = powf(p.ad, (float)S);
  const float gSa = powf(p.aa, (float)S);

  if (t < 3) { carry[t][0] = 0.0f; carry[t][1] = 0.0f; }  // y0 = 0

  // 10 NAMED prefetch registers + 10 NAMED hoisted LDS addresses.
#define DECL_R(K) f32x4 r##K;
  REPEAT10(DECL_R)
#undef DECL_R
#define DECL_A(K) const int a##K = ((t + K * 256) / F4C) * PADS \
                                   + ((t + K * 256) % F4C) * 4;
  REPEAT10(DECL_A)
#undef DECL_A
  const f32x4* xg4 = reinterpret_cast<const f32x4*>(xs);

#define LD1(K) { int i_ = t + K * 256; r##K = xg_[i_ < nf4_ ? i_ : 0]; }
#define LD_TILE(TILE)                                                        \
  do {                                                                       \
    const int nf4_ = ((TILE) == NSEG - 1) ? TAIL_F4 : TILE_F4;               \
    const f32x4* xg_ = xg4 + (size_t)(TILE) * TILE_F4;                       \
    REPEAT10(LD1)                                                            \
  } while (0)
#define WR1(K) *reinterpret_cast<f32x4*>(buf + a##K) = r##K;
#define WR_TILE() do { REPEAT10(WR1) } while (0)

  LD_TILE(0);
  WR_TILE();
  __syncthreads();                            // buf ready; carries visible

  for (int g = 0; g < NSEG; ++g) {
    const bool pf = (g + 1 < NSEG);
    if (pf) LD_TILE(g + 1);                   // issue next-segment loads NOW
    __builtin_amdgcn_sched_barrier(0);        // pin issue before compute

    const int  c     = g * CHT + t;
    const bool valid = c < NC;
    const float* my  = buf + t * PADS;
    float* myw       = buf + t * PADS;

    // ---- mode 0: decay env of |x| -> chunk map; scan -> ydI --------------
    float A = -INFINITY, B = 0.0f;
#pragma unroll
    for (int i = 0; i < F4C; ++i) {
      f32x4 v = *reinterpret_cast<const f32x4*>(my + 4 * i);
#pragma unroll
      for (int j = 0; j < 4; ++j) {
        float xa = fabsf(v[j]);
        float bx = p.bd * xa;
        A = fmaxf(xa, fmaf(p.ad, A, bx));
        B = fmaf(p.ad, B, bx);
      }
    }
    const float ydI = seg_scan<0>(A, B, valid, gSd, wAm[0], wBm[0], wGm[0],
                                  carry[0], g, t);

    // ---- mode 1: attack env of yd -> chunk map; scan -> yaI --------------
    {
      float yd = ydI;
      A = INFINITY; B = 0.0f;
#pragma unroll
      for (int i = 0; i < F4C; ++i) {
        f32x4 v = *reinterpret_cast<const f32x4*>(my + 4 * i);
#pragma unroll
        for (int j = 0; j < 4; ++j) {
          float xa = fabsf(v[j]);
          yd = fmaxf(xa, fmaf(p.ad, yd, p.bd * xa));
          float by = p.ba * yd;
          A = fminf(yd, fmaf(p.aa, A, by));
          B = fmaf(p.aa, B, by);
        }
      }
    }
    const float yaI = seg_scan<1>(A, B, valid, gSa, wAm[1], wBm[1], wGm[1],
                                  carry[1], g, t);

    // ---- mode 2: decay env of et -> chunk map; scan -> yeI ---------------
    {
      float yd = ydI, ya = yaI;
      A = -INFINITY; B = 0.0f;
#pragma unroll
      for (int i = 0; i < F4C; ++i) {
        f32x4 v = *reinterpret_cast<const f32x4*>(my + 4 * i);
#pragma unroll
        for (int j = 0; j < 4; ++j) {
          float xa = fabsf(v[j]);
          yd = fmaxf(xa, fmaf(p.ad, yd, p.bd * xa));
          ya = fminf(yd, fmaf(p.aa, ya, p.ba * yd));
          float et = fmaxf((yd - ya) - p.nuamp, 0.0f);
          float bx = p.bd * et;
          A = fmaxf(et, fmaf(p.ad, A, bx));
          B = fmaf(p.ad, B, bx);
        }
      }
    }
    const float yeI = seg_scan<0>(A, B, valid, gSd, wAm[2], wBm[2], wGm[2],
                                  carry[2], g, t);

    // ---- mode 3: final modulation, in-place into buf ---------------------
    {
      float yd = ydI, ya = yaI, ye = yeI;
#pragma unroll
      for (int i = 0; i < F4C; ++i) {
        f32x4 v = *reinterpret_cast<const f32x4*>(my + 4 * i);
        f32x4 oo;
#pragma unroll
        for (int j = 0; j < 4; ++j) {
          float xa = fabsf(v[j]);
          yd = fmaxf(xa, fmaf(p.ad, yd, p.bd * xa));
          ya = fminf(yd, fmaf(p.aa, ya, p.ba * yd));
          float et = fmaxf((yd - ya) - p.nuamp, 0.0f);
          ye = fmaxf(et, fmaf(p.ad, ye, p.bd * et));
          oo[j] = v[j] * (et / (ye + p.reg));
        }
        *reinterpret_cast<f32x4*>(myw + 4 * i) = oo;
      }
    }
    __syncthreads();                          // results visible for transpose

    // ---- coalesced nontemporal out-store (reads own aK slots) ------------
    {
      f32x4* og = reinterpret_cast<f32x4*>(os) + (size_t)g * TILE_F4;
      const int nf4o = pf ? TILE_F4 : TAIL_F4;
#define ST1(K) { int i_ = t + K * 256;                                        \
                 if (i_ < nf4o)                                               \
                   __builtin_nontemporal_store(                               \
                     *reinterpret_cast<const f32x4*>(buf + a##K), &og[i_]); }
      REPEAT10(ST1)
#undef ST1
    }
    if (pf) WR_TILE();                        // own slots: read-then-write OK
    __syncthreads();                          // buf stable for next segment
  }
#undef LD1
#undef LD_TILE
#undef WR1
#undef WR_TILE
}

extern "C" void kernel_launch(void* const* d_in, const int* in_sizes, int n_in,
                              void* d_out, int out_size, void* d_ws, size_t ws_size,
                              hipStream_t stream) {
  const float* x     = (const float*)d_in[0];
  const float* tauA  = (const float*)d_in[1];
  const float* tauD  = (const float*)d_in[2];
  const float* nu    = (const float*)d_in[3];
  const float* dbreg = (const float*)d_in[4];
  float* out = (float*)d_out;
  const int nseries = in_sizes[0] / kT;       // 256
  (void)d_ws; (void)ws_size;                  // no workspace needed

  k_one<<<nseries, 256, 0, stream>>>(x, tauA, tauD, nu, dbreg, out);
}